// Round 10
// baseline (605.061 us; speedup 1.0000x reference)
//
#include <hip/hip_runtime.h>
#include <hip/hip_bf16.h>

#define N_NODES 100000
#define N_EDGES 300000
#define CH 256
#define EPS 1e-5f
#define AGG_BLOCKS 3125   // N_NODES / 32 exactly
#define Y_TILES 782       // ceil(N_NODES/128)
#define Y_TILES_PAD 784   // padded to multiple of 8
#define CAST_CHUNK 5000   // cast blocks carried by each CSR-chain kernel (5x = 25000)

typedef __hip_bfloat16 bf16;
typedef __attribute__((ext_vector_type(8))) short bf16x8_t;  // 8 bf16 (4 VGPRs)
typedef __attribute__((ext_vector_type(4))) float f32x4_t;   // 4 fp32 acc

__device__ __forceinline__ unsigned short f2bf(float f) {
    bf16 h = __float2bfloat16(f);
    return __builtin_bit_cast(unsigned short, h);
}
__device__ __forceinline__ float bflo(unsigned int w) {
    return __builtin_bit_cast(float, w << 16);
}
__device__ __forceinline__ float bfhi(unsigned int w) {
    return __builtin_bit_cast(float, w & 0xffff0000u);
}
__device__ __forceinline__ unsigned pack2(float a, float b) {
    return (unsigned)f2bf(a) | ((unsigned)f2bf(b) << 16);
}
__device__ __forceinline__ void store_val(bf16* p, float v) { *p = __float2bfloat16(v); }

__device__ __forceinline__ void async_copy16(const void* g, void* l) {
    __builtin_amdgcn_global_load_lds((const __attribute__((address_space(1))) void*)g,
                                     (__attribute__((address_space(3))) void*)l, 16, 0, 0);
}

// fp32->bf16 cast of one float4 chunk (rides along in CSR-chain kernels' idle BW)
__device__ __forceinline__ void cast_chunk(const float* __restrict__ x,
                                           unsigned short* __restrict__ y, int i) {
    float4 v = ((const float4*)x)[i];
    ushort4 o;
    o.x = f2bf(v.x); o.y = f2bf(v.y); o.z = f2bf(v.z); o.w = f2bf(v.w);
    ((ushort4*)y)[i] = o;
}

// ================= CSR build (each kernel carries CAST_CHUNK cast blocks) =================
__global__ void k_zero_int(int* __restrict__ p, int n,
                           const float* __restrict__ cx, unsigned short* __restrict__ cy,
                           int castBase, int nbMain) {
    if ((int)blockIdx.x >= nbMain) {
        cast_chunk(cx, cy, (castBase + (int)blockIdx.x - nbMain) * 256 + (int)threadIdx.x);
        return;
    }
    int i = blockIdx.x * 256 + threadIdx.x;
    if (i < n) p[i] = 0;
}
__global__ void k_count_deg(const int* __restrict__ dst, int* __restrict__ deg,
                            const float* __restrict__ cx, unsigned short* __restrict__ cy,
                            int castBase, int nbMain) {
    if ((int)blockIdx.x >= nbMain) {
        cast_chunk(cx, cy, (castBase + (int)blockIdx.x - nbMain) * 256 + (int)threadIdx.x);
        return;
    }
    int e = blockIdx.x * 256 + threadIdx.x;
    if (e < N_EDGES) atomicAdd(&deg[dst[e]], 1);
}
// block sums for scan + dinv (merged: same pass over deg)
__global__ void k_block_sums(const int* __restrict__ deg, int* __restrict__ bsum,
                             float* __restrict__ dinv,
                             const float* __restrict__ cx, unsigned short* __restrict__ cy,
                             int castBase, int nbMain) {
    if ((int)blockIdx.x >= nbMain) {
        cast_chunk(cx, cy, (castBase + (int)blockIdx.x - nbMain) * 256 + (int)threadIdx.x);
        return;
    }
    __shared__ int s[256];
    int t = threadIdx.x;
    int i = blockIdx.x * 256 + t;
    int v = (i < N_NODES) ? deg[i] : 0;
    s[t] = v;
    if (i < N_NODES) dinv[i] = rsqrtf((float)(v + 1));  // +1 self loop
    __syncthreads();
    for (int off = 128; off > 0; off >>= 1) {
        if (t < off) s[t] += s[t + off];
        __syncthreads();
    }
    if (t == 0) bsum[blockIdx.x] = s[0];
}
__global__ void k_scan_bsums(int* __restrict__ bsum, int nb) {
    __shared__ int s[512];
    int t = threadIdx.x;
    int v = (t < nb) ? bsum[t] : 0;
    s[t] = v;
    __syncthreads();
    for (int off = 1; off < 512; off <<= 1) {
        int u = (t >= off) ? s[t - off] : 0;
        __syncthreads();
        s[t] += u;
        __syncthreads();
    }
    if (t < nb) bsum[t] = s[t] - v;  // exclusive
}
__global__ void k_row_ptr(const int* __restrict__ deg, const int* __restrict__ bsum,
                          int* __restrict__ row_ptr,
                          const float* __restrict__ cx, unsigned short* __restrict__ cy,
                          int castBase, int nbMain) {
    if ((int)blockIdx.x >= nbMain) {
        cast_chunk(cx, cy, (castBase + (int)blockIdx.x - nbMain) * 256 + (int)threadIdx.x);
        return;
    }
    __shared__ int s[256];
    int t = threadIdx.x;
    int i = blockIdx.x * 256 + t;
    int v = (i < N_NODES) ? deg[i] : 0;
    s[t] = v;
    __syncthreads();
    for (int off = 1; off < 256; off <<= 1) {
        int u = (t >= off) ? s[t - off] : 0;
        __syncthreads();
        s[t] += u;
        __syncthreads();
    }
    if (i < N_NODES) row_ptr[i] = bsum[blockIdx.x] + s[t] - v;  // exclusive
    if (blockIdx.x == 0 && t == 0) row_ptr[N_NODES] = N_EDGES;
}
// scatter also precomputes per-edge weight wedge = dinv[d]*dinv[s], the original
// edge id, and the row (dst) node of each CSR slot for edge-parallel CSR passes.
__global__ void k_scatter(const int* __restrict__ src, const int* __restrict__ dst,
                          const int* __restrict__ row_ptr, int* __restrict__ cursor,
                          const float* __restrict__ dinv,
                          int* __restrict__ col, float* __restrict__ wedge,
                          int* __restrict__ eid, int* __restrict__ rowid,
                          const float* __restrict__ cx, unsigned short* __restrict__ cy,
                          int castBase, int nbMain) {
    if ((int)blockIdx.x >= nbMain) {
        cast_chunk(cx, cy, (castBase + (int)blockIdx.x - nbMain) * 256 + (int)threadIdx.x);
        return;
    }
    int e = blockIdx.x * 256 + threadIdx.x;
    if (e < N_EDGES) {
        int d = dst[e], s = src[e];
        int p = atomicAdd(&cursor[d], 1);
        int idx = row_ptr[d] + p;
        col[idx] = s;
        wedge[idx] = dinv[d] * dinv[s];
        eid[idx] = e;
        rowid[idx] = d;
    }
}

// ================= weight transposes (W1, W2 only) =================
__global__ void k_transpose_all(const float* __restrict__ W1, const float* __restrict__ W2,
                                bf16* __restrict__ wt) {
    int which = blockIdx.x >> 8;  // 0..1
    int idx = ((blockIdx.x & 255) << 8) + threadIdx.x;
    int n = idx >> 8, k = idx & 255;
    const float* W = which ? W2 : W1;
    wt[(size_t)which * 65536 + (size_t)n * 256 + k] =
        __float2bfloat16(W[(size_t)k * 256 + n]);
}

// ============ fused layer-3 + link-pred weights (+ fused bias in block 256) ============
// W3fc^T[n][k] = sum_j W3[k][j] * F[j][n], F[j][n] = fc1_w[(n<256? j : 256+j)][n&255]
// Output 512x256 = 2*65536 bf16. Block 256: b3fc[n] = sum_j b3[j]*F[j][n] + (n<256?fc1_b[n]:0)
__global__ void k_fuse_w(const float* __restrict__ W3, const float* __restrict__ fc1w,
                         const float* __restrict__ b3, const float* __restrict__ fc1b,
                         bf16* __restrict__ wtf, float* __restrict__ bout) {
    int n = threadIdx.x;      // 0..511
    int nc = n & 255;
    size_t ro = (n < 256) ? 0 : 256;
    if (blockIdx.x == 256) {  // fused bias (uniform per block, no barrier crossed)
        float acc = (n < 256) ? fc1b[n] : 0.f;
#pragma unroll 4
        for (int j = 0; j < 256; ++j)
            acc += b3[j] * fc1w[(ro + j) * 256 + nc];
        bout[n] = acc;
        return;
    }
    __shared__ float w3row[256];
    int k = blockIdx.x;       // 0..255
    if (n < 256) w3row[n] = W3[(size_t)k * 256 + n];
    __syncthreads();
    float acc = 0.f;
#pragma unroll 4
    for (int j = 0; j < 256; ++j)
        acc += w3row[j] * fc1w[(ro + j) * 256 + nc];
    wtf[(size_t)n * 256 + k] = __float2bfloat16(acc);
}

// ====== bf16 MFMA GEMM — 8 waves / 512 threads, 32KB LDS, occupancy-first ======
// C[M x (NX*128)] = A @ Bt^T + bias. 128x128 tile, BK=64, 4 K-steps.
// Wave tile 32x64 (acc[2][4] = 32 VGPR) so __launch_bounds__(512,6) caps VGPR
// ~85 -> 6 waves/SIMD = 24 waves/CU: latency hidden by TLP.
// STATS: per-row-tile column sum/sumsq partials (BN input stats) -> part.
template <int NX, bool BIAS, bool STATS>
__global__ __launch_bounds__(512, 6) void k_gemm_mfma(const bf16* __restrict__ A,
                                                      const bf16* __restrict__ Bt,
                                                      bf16* __restrict__ C, int M, int ldc,
                                                      const float* __restrict__ bias,
                                                      float* __restrict__ part) {
    constexpr int LOG2NX = (NX == 4) ? 2 : 1;
    int id = blockIdx.x;
    int rg = (id & 7) + 8 * (id >> (3 + LOG2NX));
    int ct = (id >> 3) & (NX - 1);
    if (rg >= Y_TILES) return;
    const int row0 = rg * 128;
    const int col0 = ct * 128;

    __shared__ bf16 As[128 * 64];   // 16 KB
    __shared__ bf16 Bs[128 * 64];   // 16 KB
    __shared__ float sS[4][128];
    __shared__ float sQ[4][128];
    const int tid = threadIdx.x;
    const int lane = tid & 63;
    const int w = tid >> 6;          // 0..7
    const int wr = w >> 1, wc = w & 1;   // wr 0..3 (32-row strips), wc 0..1 (64-col)
    const int lr = lane & 15, quad = lane >> 4;

    f32x4_t acc[2][4] = {};

    for (int k0 = 0; k0 < 256; k0 += 64) {
#pragma unroll
        for (int i = 0; i < 2; ++i) {
            int j = i * 512 + tid;        // 1024 chunks of 16B per buffer
            int r = j >> 3, c = j & 7;
            int gk = ((c ^ (r & 7)) << 3);
            int gr = row0 + r; gr = gr < M ? gr : M - 1;
            async_copy16(A + (size_t)gr * 256 + k0 + gk, (void*)(As + j * 8));
            async_copy16(Bt + (size_t)(col0 + r) * 256 + k0 + gk, (void*)(Bs + j * 8));
        }
        __syncthreads();
#pragma unroll
        for (int ks = 0; ks < 2; ++ks) {
            bf16x8_t af[2], bfr[4];
#pragma unroll
            for (int mi = 0; mi < 2; ++mi) {
                int m = wr * 32 + mi * 16 + lr;
                int c = (ks * 4 + quad) ^ (m & 7);
                af[mi] = *(const bf16x8_t*)(As + m * 64 + c * 8);
            }
#pragma unroll
            for (int ni = 0; ni < 4; ++ni) {
                int n = wc * 64 + ni * 16 + lr;
                int c = (ks * 4 + quad) ^ (n & 7);
                bfr[ni] = *(const bf16x8_t*)(Bs + n * 64 + c * 8);
            }
#pragma unroll
            for (int mi = 0; mi < 2; ++mi)
#pragma unroll
                for (int ni = 0; ni < 4; ++ni)
                    acc[mi][ni] = __builtin_amdgcn_mfma_f32_16x16x32_bf16(
                        af[mi], bfr[ni], acc[mi][ni], 0, 0, 0);
        }
        __syncthreads();
    }
    // bias into acc (so stats include it)
#pragma unroll
    for (int ni = 0; ni < 4; ++ni) {
        int colg = col0 + wc * 64 + ni * 16 + lr;
        float bv = BIAS ? bias[colg] : 0.f;
#pragma unroll
        for (int mi = 0; mi < 2; ++mi)
#pragma unroll
            for (int r = 0; r < 4; ++r) acc[mi][ni][r] += bv;
    }
    if (STATS) {
        float cs[4] = {}, cq[4] = {};
#pragma unroll
        for (int mi = 0; mi < 2; ++mi)
#pragma unroll
            for (int r = 0; r < 4; ++r) {
                int row = row0 + wr * 32 + mi * 16 + quad * 4 + r;
                if (row < M) {
#pragma unroll
                    for (int ni = 0; ni < 4; ++ni) {
                        float v = acc[mi][ni][r];
                        cs[ni] += v;
                        cq[ni] += v * v;
                    }
                }
            }
        // sum across the 4 quads (lanes lr, lr+16, lr+32, lr+48)
#pragma unroll
        for (int ni = 0; ni < 4; ++ni) {
            cs[ni] += __shfl_xor(cs[ni], 16, 64);
            cs[ni] += __shfl_xor(cs[ni], 32, 64);
            cq[ni] += __shfl_xor(cq[ni], 16, 64);
            cq[ni] += __shfl_xor(cq[ni], 32, 64);
        }
        if (quad == 0) {
#pragma unroll
            for (int ni = 0; ni < 4; ++ni) {
                int cc = wc * 64 + ni * 16 + lr;
                sS[wr][cc] = cs[ni];
                sQ[wr][cc] = cq[ni];
            }
        }
        __syncthreads();
        if (tid < 128) {
            float ss = sS[0][tid] + sS[1][tid] + sS[2][tid] + sS[3][tid];
            float qq = sQ[0][tid] + sQ[1][tid] + sQ[2][tid] + sQ[3][tid];
            int cg = col0 + tid;
            part[(size_t)rg * 512 + cg] = ss;
            part[(size_t)rg * 512 + 256 + cg] = qq;
        }
    }
#pragma unroll
    for (int mi = 0; mi < 2; ++mi) {
#pragma unroll
        for (int r = 0; r < 4; ++r) {
            int row = row0 + wr * 32 + mi * 16 + quad * 4 + r;
            if (row < M) {
#pragma unroll
                for (int ni = 0; ni < 4; ++ni) {
                    int colg = col0 + wc * 64 + ni * 16 + lr;
                    store_val(C + (size_t)row * ldc + colg, acc[mi][ni][r]);
                }
            }
        }
    }
}

// expand a uint4 of 8 bf16 into 8 floats, optionally applying BN(scale,shift)+relu
template <bool BN>
__device__ __forceinline__ void expand8(uint4 m, const float* sc, const float* sh, float* r) {
    r[0] = bflo(m.x); r[1] = bfhi(m.x); r[2] = bflo(m.y); r[3] = bfhi(m.y);
    r[4] = bflo(m.z); r[5] = bfhi(m.z); r[6] = bflo(m.w); r[7] = bfhi(m.w);
    if (BN) {
#pragma unroll
        for (int i = 0; i < 8; ++i) r[i] = fmaxf(r[i] * sc[i] + sh[i], 0.f);
    }
}

// ===== CSR aggregation y = A_hat x' (+bias) : 32 lanes/node, 32 nodes/block.
// The 4 nodes of each half-wave are processed POSITION-INTERLEAVED: each loop
// iteration issues up to 4 independent col/wedge loads + 4 independent row
// gathers (4 parallel chains instead of one 2-deep chain) -> more MLP.
// BN: x' = relu(x*scale+shift) on the fly. STATS: post-bias per-block column
// sum/sumsq partials -> part[block][512] (BN stats over the OUTPUT h).
template <bool BN, bool STATS>
__global__ __launch_bounds__(256) void k_agg_csr(const unsigned short* __restrict__ x,
                                                 const int* __restrict__ row_ptr,
                                                 const int* __restrict__ col,
                                                 const float* __restrict__ wedge,
                                                 const float* __restrict__ dinv,
                                                 const float* __restrict__ scale,
                                                 const float* __restrict__ shift,
                                                 const float* __restrict__ bias,
                                                 bf16* __restrict__ out,
                                                 float* __restrict__ part) {
    __shared__ float sred[8][256];
    __shared__ float qred[8][256];
    int g = threadIdx.x >> 5, lh = threadIdx.x & 31;  // 8 half-waves x 32 lanes
    int base = blockIdx.x * 32 + g * 4;               // exact: AGG_BLOCKS*32 == N_NODES
    const uint4* xv = (const uint4*)x;                // bf16 row = 32 uint4
    float sc[8], sh[8], bs[8];
    if (BN) {
        float4 a = ((const float4*)scale)[lh * 2];
        float4 b = ((const float4*)scale)[lh * 2 + 1];
        float4 c = ((const float4*)shift)[lh * 2];
        float4 d = ((const float4*)shift)[lh * 2 + 1];
        sc[0] = a.x; sc[1] = a.y; sc[2] = a.z; sc[3] = a.w;
        sc[4] = b.x; sc[5] = b.y; sc[6] = b.z; sc[7] = b.w;
        sh[0] = c.x; sh[1] = c.y; sh[2] = c.z; sh[3] = c.w;
        sh[4] = d.x; sh[5] = d.y; sh[6] = d.z; sh[7] = d.w;
    }
    if (STATS) {
        float4 e = ((const float4*)bias)[lh * 2];
        float4 f = ((const float4*)bias)[lh * 2 + 1];
        bs[0] = e.x; bs[1] = e.y; bs[2] = e.z; bs[3] = e.w;
        bs[4] = f.x; bs[5] = f.y; bs[6] = f.z; bs[7] = f.w;
    }
    // row_ptr for 4 consecutive nodes (5 contiguous ints)
    int rp0 = row_ptr[base], rp1 = row_ptr[base + 1], rp2 = row_ptr[base + 2],
        rp3 = row_ptr[base + 3], rp4 = row_ptr[base + 4];
    // 4 self rows in flight
    uint4 xr0 = xv[(size_t)(base + 0) * 32 + lh];
    uint4 xr1 = xv[(size_t)(base + 1) * 32 + lh];
    uint4 xr2 = xv[(size_t)(base + 2) * 32 + lh];
    uint4 xr3 = xv[(size_t)(base + 3) * 32 + lh];
    float dv0 = dinv[base + 0], dv1 = dinv[base + 1];
    float dv2 = dinv[base + 2], dv3 = dinv[base + 3];
    float a[4][8];
    {
        float r[8];
        expand8<BN>(xr0, sc, sh, r);
#pragma unroll
        for (int t = 0; t < 8; ++t) a[0][t] = dv0 * dv0 * r[t];
        expand8<BN>(xr1, sc, sh, r);
#pragma unroll
        for (int t = 0; t < 8; ++t) a[1][t] = dv1 * dv1 * r[t];
        expand8<BN>(xr2, sc, sh, r);
#pragma unroll
        for (int t = 0; t < 8; ++t) a[2][t] = dv2 * dv2 * r[t];
        expand8<BN>(xr3, sc, sh, r);
#pragma unroll
        for (int t = 0; t < 8; ++t) a[3][t] = dv3 * dv3 * r[t];
    }
    // position-interleaved edge loop over the 4 nodes
    int p0 = rp0, p1 = rp1, p2 = rp2, p3 = rp3;
    while ((p0 < rp1) | (p1 < rp2) | (p2 < rp3) | (p3 < rp4)) {
        bool v0 = p0 < rp1, v1 = p1 < rp2, v2 = p2 < rp3, v3 = p3 < rp4;
        int c0, c1, c2, c3;
        float w0, w1, w2, w3;
        uint4 m0, m1, m2, m3;
        if (v0) { c0 = col[p0]; w0 = wedge[p0]; }
        if (v1) { c1 = col[p1]; w1 = wedge[p1]; }
        if (v2) { c2 = col[p2]; w2 = wedge[p2]; }
        if (v3) { c3 = col[p3]; w3 = wedge[p3]; }
        if (v0) m0 = xv[(size_t)c0 * 32 + lh];
        if (v1) m1 = xv[(size_t)c1 * 32 + lh];
        if (v2) m2 = xv[(size_t)c2 * 32 + lh];
        if (v3) m3 = xv[(size_t)c3 * 32 + lh];
        if (v0) {
            float r[8];
            expand8<BN>(m0, sc, sh, r);
#pragma unroll
            for (int t = 0; t < 8; ++t) a[0][t] += w0 * r[t];
            ++p0;
        }
        if (v1) {
            float r[8];
            expand8<BN>(m1, sc, sh, r);
#pragma unroll
            for (int t = 0; t < 8; ++t) a[1][t] += w1 * r[t];
            ++p1;
        }
        if (v2) {
            float r[8];
            expand8<BN>(m2, sc, sh, r);
#pragma unroll
            for (int t = 0; t < 8; ++t) a[2][t] += w2 * r[t];
            ++p2;
        }
        if (v3) {
            float r[8];
            expand8<BN>(m3, sc, sh, r);
#pragma unroll
            for (int t = 0; t < 8; ++t) a[3][t] += w3 * r[t];
            ++p3;
        }
    }
    float s8[8] = {}, q8[8] = {};
#pragma unroll
    for (int n = 0; n < 4; ++n) {
        if (STATS) {
#pragma unroll
            for (int t = 0; t < 8; ++t) {
                a[n][t] += bs[t];
                s8[t] += a[n][t];
                q8[t] += a[n][t] * a[n][t];
            }
        }
        uint4 o;
        o.x = pack2(a[n][0], a[n][1]); o.y = pack2(a[n][2], a[n][3]);
        o.z = pack2(a[n][4], a[n][5]); o.w = pack2(a[n][6], a[n][7]);
        ((uint4*)(out + (size_t)(base + n) * CH))[lh] = o;
    }
    if (STATS) {
#pragma unroll
        for (int j = 0; j < 8; ++j) {
            sred[g][lh * 8 + j] = s8[j];
            qred[g][lh * 8 + j] = q8[j];
        }
        __syncthreads();
        int t = threadIdx.x;  // channel 0..255
        float ss = 0.f, qq = 0.f;
#pragma unroll
        for (int gg = 0; gg < 8; ++gg) {
            ss += sred[gg][t];
            qq += qred[gg][t];
        }
        part[(size_t)blockIdx.x * 512 + t] = ss;
        part[(size_t)blockIdx.x * 512 + 256 + t] = qq;
    }
}

// one wave per channel: lanes stride over npart partials, shuffle-reduce
__global__ __launch_bounds__(256) void k_bn_finalize(const float* __restrict__ part,
                                                     const float* __restrict__ g,
                                                     const float* __restrict__ be,
                                                     float* __restrict__ scale,
                                                     float* __restrict__ shift, int npart) {
    int wave = threadIdx.x >> 6, lane = threadIdx.x & 63;
    int c = blockIdx.x * 4 + wave;  // 0..255
    float s = 0.f, q = 0.f;
    for (int j = lane; j < npart; j += 64) {
        s += part[(size_t)j * 512 + c];
        q += part[(size_t)j * 512 + 256 + c];
    }
#pragma unroll
    for (int off = 32; off > 0; off >>= 1) {
        s += __shfl_down(s, off, 64);
        q += __shfl_down(q, off, 64);
    }
    if (lane == 0) {
        float mu = s * (1.0f / N_NODES);
        float var = q * (1.0f / N_NODES) - mu * mu;
        float sc = g[c] * rsqrtf(var + EPS);
        scale[c] = sc;
        shift[c] = be[c] - mu * sc;
    }
}

// ======= edge scoring: edge-parallel over CSR (dst-sorted) slots =======
// 4 slots/wave, 16 lanes each, 16 ch/lane; consecutive quarters share the
// same/nearby dst rows (v[dst] L1/L2-resident). Blocks XCD-swizzled (bijective).
__global__ __launch_bounds__(256) void k_edge_score(
        const unsigned short* __restrict__ uv,
        const int* __restrict__ col, const int* __restrict__ eid,
        const int* __restrict__ rowid, const int* __restrict__ neg,
        const float* __restrict__ fc2_w, const float* __restrict__ fc2_b,
        float* __restrict__ out) {
    constexpr int NWG = 18750;          // N_EDGES / 16
    constexpr int Q = NWG / 8, R = NWG % 8;  // 2343, 6
    int bid = blockIdx.x;
    int xcd = bid & 7, ord = bid >> 3;
    int swz = ((xcd < R) ? xcd * (Q + 1) : R * (Q + 1) + (xcd - R) * Q) + ord;
    int wave = threadIdx.x >> 6, lane = threadIdx.x & 63;
    int qtr = lane >> 4, l = lane & 15;
    int i = swz * 16 + wave * 4 + qtr;  // CSR slot, NWG*16 == N_EDGES exactly
    int s = col[i], d = rowid[i], e = eid[i];
    int g = neg[e];
    const uint4* uvv = (const uint4*)uv;  // row = 64 uint4 (u: 0..31, v: 32..63)
    uint4 u0 = uvv[(size_t)s * 64 + l * 2];
    uint4 u1 = uvv[(size_t)s * 64 + l * 2 + 1];
    uint4 p0 = uvv[(size_t)d * 64 + 32 + l * 2];
    uint4 p1 = uvv[(size_t)d * 64 + 33 + l * 2];
    uint4 n0 = uvv[(size_t)g * 64 + 32 + l * 2];
    uint4 n1 = uvv[(size_t)g * 64 + 33 + l * 2];
    float4 w0 = ((const float4*)fc2_w)[l * 4];
    float4 w1 = ((const float4*)fc2_w)[l * 4 + 1];
    float4 w2 = ((const float4*)fc2_w)[l * 4 + 2];
    float4 w3 = ((const float4*)fc2_w)[l * 4 + 3];

    float t0 = bflo(u0.x), t1 = bfhi(u0.x), t2 = bflo(u0.y), t3 = bfhi(u0.y);
    float t4 = bflo(u0.z), t5 = bfhi(u0.z), t6 = bflo(u0.w), t7 = bfhi(u0.w);
    float t8 = bflo(u1.x), t9 = bfhi(u1.x), ta = bflo(u1.y), tb = bfhi(u1.y);
    float tc = bflo(u1.z), td = bfhi(u1.z), te = bflo(u1.w), tf = bfhi(u1.w);

    float accp =
        fmaxf(t0 + bflo(p0.x), 0.f) * w0.x + fmaxf(t1 + bfhi(p0.x), 0.f) * w0.y +
        fmaxf(t2 + bflo(p0.y), 0.f) * w0.z + fmaxf(t3 + bfhi(p0.y), 0.f) * w0.w +
        fmaxf(t4 + bflo(p0.z), 0.f) * w1.x + fmaxf(t5 + bfhi(p0.z), 0.f) * w1.y +
        fmaxf(t6 + bflo(p0.w), 0.f) * w1.z + fmaxf(t7 + bfhi(p0.w), 0.f) * w1.w +
        fmaxf(t8 + bflo(p1.x), 0.f) * w2.x + fmaxf(t9 + bfhi(p1.x), 0.f) * w2.y +
        fmaxf(ta + bflo(p1.y), 0.f) * w2.z + fmaxf(tb + bfhi(p1.y), 0.f) * w2.w +
        fmaxf(tc + bflo(p1.z), 0.f) * w3.x + fmaxf(td + bfhi(p1.z), 0.f) * w3.y +
        fmaxf(te + bflo(p1.w), 0.f) * w3.z + fmaxf(tf + bfhi(p1.w), 0.f) * w3.w;
    float accn =
        fmaxf(t0 + bflo(n0.x), 0.f) * w0.x + fmaxf(t1 + bfhi(n0.x), 0.f) * w0.y +
        fmaxf(t2 + bflo(n0.y), 0.f) * w0.z + fmaxf(t3 + bfhi(n0.y), 0.f) * w0.w +
        fmaxf(t4 + bflo(n0.z), 0.f) * w1.x + fmaxf(t5 + bfhi(n0.z), 0.f) * w1.y +
        fmaxf(t6 + bflo(n0.w), 0.f) * w1.z + fmaxf(t7 + bfhi(n0.w), 0.f) * w1.w +
        fmaxf(t8 + bflo(n1.x), 0.f) * w2.x + fmaxf(t9 + bfhi(n1.x), 0.f) * w2.y +
        fmaxf(ta + bflo(n1.y), 0.f) * w2.z + fmaxf(tb + bfhi(n1.y), 0.f) * w2.w +
        fmaxf(tc + bflo(n1.z), 0.f) * w3.x + fmaxf(td + bfhi(n1.z), 0.f) * w3.y +
        fmaxf(te + bflo(n1.w), 0.f) * w3.z + fmaxf(tf + bfhi(n1.w), 0.f) * w3.w;
#pragma unroll
    for (int off = 8; off > 0; off >>= 1) {
        accp += __shfl_down(accp, off, 64);
        accn += __shfl_down(accn, off, 64);
    }
    if (l == 0) {
        float bb = fc2_b[0];
        out[e] = 1.0f / (1.0f + expf(-(accp + bb)));
        out[N_EDGES + e] = 1.0f / (1.0f + expf(-(accn + bb)));
    }
}

extern "C" void kernel_launch(void* const* d_in, const int* in_sizes, int n_in,
                              void* d_out, int out_size, void* d_ws, size_t ws_size,
                              hipStream_t stream) {
    const float* node_feat = (const float*)d_in[0];
    const int* src = (const int*)d_in[1];
    const int* dst = (const int*)d_in[2];
    const int* neg = (const int*)d_in[3];
    const float* W1 = (const float*)d_in[4];  const float* b1 = (const float*)d_in[5];
    const float* W2 = (const float*)d_in[6];  const float* b2 = (const float*)d_in[7];
    const float* W3 = (const float*)d_in[8];  const float* b3 = (const float*)d_in[9];
    const float* g1 = (const float*)d_in[10]; const float* be1 = (const float*)d_in[11];
    const float* g2 = (const float*)d_in[12]; const float* be2 = (const float*)d_in[13];
    const float* fc1_w = (const float*)d_in[14]; const float* fc1_b = (const float*)d_in[15];
    const float* fc2_w = (const float*)d_in[16]; const float* fc2_b = (const float*)d_in[17];
    float* out = (float*)d_out;

    // ---- workspace layout ----
    const size_t NF = (size_t)N_NODES * CH;  // 25,600,000
    bf16* UV = (bf16*)d_ws;                  // [node][512] u|v (2*NF)
    bf16* Xbf = UV + 2 * NF;                 // ping buffer (NF)
    bf16* XwBf = Xbf + NF;                   // pong buffer (NF)
    bf16* wt = XwBf + NF;                    // 4*65536: W1t(1) W2t(1) W3fc_t(2 - 512x256)
    float* dinv = (float*)(wt + 4 * 65536);
    float* bnpart = dinv + N_NODES;          // AGG_BLOCKS * 512 (6.4 MB, covers both uses)
    float* scale = bnpart + (size_t)AGG_BLOCKS * 512;
    float* shift = scale + CH;
    float* b3fc = shift + CH;                // 512 fused bias
    float* wedge = b3fc + 512;               // E floats
    int* ideg = (int*)(wedge + N_EDGES);     // N (cursor follows: zeroed together)
    int* cursor = ideg + N_NODES;
    int* row_ptr = cursor + N_NODES;
    int* col = row_ptr + N_NODES + 1;
    int* eid = col + N_EDGES;                // E ints (original edge id per CSR slot)
    int* rowid = eid + N_EDGES;              // E ints (dst node per CSR slot)
    int* bsum = rowid + N_EDGES;             // 512
    (void)ws_size;

    int gemmBlocks = 2 * Y_TILES_PAD;          // 1568 (N=256, NX=2)
    int uvBlocks = 4 * Y_TILES_PAD;            // 3136 (N=512, NX=4)
    int nodeBlocks = (N_NODES + 255) / 256;    // 391
    int edgeBlocks = (N_EDGES + 255) / 256;    // 1172
    int zeroBlocks = (2 * N_NODES + 255) / 256;// 782
    int scoreBlocks = N_EDGES / 16;            // 18750 (4 CSR slots per wave)
    unsigned short* Xc = (unsigned short*)Xbf; // cast destination

    // ---- CSR build + dinv + edge weights (each kernel carries 5000 cast blocks;
    //      5 x 5000 x 1024 elems == NF exactly -> Xbf fully cast before gemm1) ----
    k_zero_int<<<zeroBlocks + CAST_CHUNK, 256, 0, stream>>>(
        ideg, 2 * N_NODES, node_feat, Xc, 0 * CAST_CHUNK, zeroBlocks);
    k_count_deg<<<edgeBlocks + CAST_CHUNK, 256, 0, stream>>>(
        dst, ideg, node_feat, Xc, 1 * CAST_CHUNK, edgeBlocks);
    k_block_sums<<<nodeBlocks + CAST_CHUNK, 256, 0, stream>>>(
        ideg, bsum, dinv, node_feat, Xc, 2 * CAST_CHUNK, nodeBlocks);
    k_scan_bsums<<<1, 512, 0, stream>>>(bsum, nodeBlocks);
    k_row_ptr<<<nodeBlocks + CAST_CHUNK, 256, 0, stream>>>(
        ideg, bsum, row_ptr, node_feat, Xc, 3 * CAST_CHUNK, nodeBlocks);
    k_scatter<<<edgeBlocks + CAST_CHUNK, 256, 0, stream>>>(
        src, dst, row_ptr, cursor, dinv, col, wedge, eid, rowid,
        node_feat, Xc, 4 * CAST_CHUNK, edgeBlocks);

    // ---- weight prep: W1t, W2t transposes; fused W3@[Wu|Wv] (+bias, block 256) ----
    k_transpose_all<<<512, 256, 0, stream>>>(W1, W2, wt);
    k_fuse_w<<<257, 512, 0, stream>>>(W3, fc1_w, b3, fc1_b, wt + 2 * 65536, b3fc);

    // ---- layer 1: xw1 = X@W1 ; h1 = A_hat xw1 + b1 (stats in agg) ----
    k_gemm_mfma<2, false, false><<<gemmBlocks, 512, 0, stream>>>(
        Xbf, wt, XwBf, N_NODES, 256, nullptr, nullptr);
    k_agg_csr<false, true><<<AGG_BLOCKS, 256, 0, stream>>>(
        (unsigned short*)XwBf, row_ptr, col, wedge, dinv, nullptr, nullptr, b1, Xbf, bnpart);
    k_bn_finalize<<<64, 256, 0, stream>>>(bnpart, g1, be1, scale, shift, AGG_BLOCKS);

    // ---- layer 2: y2 = A_hat relu(BN(h1)) ; h2 = y2@W2 + b2 (stats in epilogue) ----
    k_agg_csr<true, false><<<AGG_BLOCKS, 256, 0, stream>>>(
        (unsigned short*)Xbf, row_ptr, col, wedge, dinv, scale, shift, nullptr, XwBf, nullptr);
    k_gemm_mfma<2, true, true><<<gemmBlocks, 512, 0, stream>>>(
        XwBf, wt + 65536, Xbf, N_NODES, 256, b2, bnpart);
    k_bn_finalize<<<64, 256, 0, stream>>>(bnpart, g2, be2, scale, shift, Y_TILES);

    // ---- layer 3 + link pred: y3 = A_hat relu(BN(h2)) ; UV = y3@W3fc + b3fc ----
    k_agg_csr<true, false><<<AGG_BLOCKS, 256, 0, stream>>>(
        (unsigned short*)Xbf, row_ptr, col, wedge, dinv, scale, shift, nullptr, XwBf, nullptr);
    k_gemm_mfma<4, true, false><<<uvBlocks, 512, 0, stream>>>(
        XwBf, wt + 2 * 65536, UV, N_NODES, 512, b3fc, nullptr);

    // ---- edge scoring ----
    k_edge_score<<<scoreBlocks, 256, 0, stream>>>((unsigned short*)UV, col, eid, rowid, neg,
                                                  fc2_w, fc2_b, out);
}

// Round 11
// 548.885 us; speedup vs baseline: 1.1023x; 1.1023x over previous
//
#include <hip/hip_runtime.h>
#include <hip/hip_bf16.h>

#define N_NODES 100000
#define N_EDGES 300000
#define CH 256
#define EPS 1e-5f
#define AGG_BLOCKS 3125   // N_NODES / 32 exactly
#define Y_TILES 782       // ceil(N_NODES/128)
#define Y_TILES_PAD 784   // padded to multiple of 8
#define CAST_CHUNK 5000   // cast blocks carried by each CSR-chain kernel (5x = 25000)

typedef __hip_bfloat16 bf16;
typedef __attribute__((ext_vector_type(8))) short bf16x8_t;  // 8 bf16 (4 VGPRs)
typedef __attribute__((ext_vector_type(4))) float f32x4_t;   // 4 fp32 acc

__device__ __forceinline__ unsigned short f2bf(float f) {
    bf16 h = __float2bfloat16(f);
    return __builtin_bit_cast(unsigned short, h);
}
__device__ __forceinline__ float bflo(unsigned int w) {
    return __builtin_bit_cast(float, w << 16);
}
__device__ __forceinline__ float bfhi(unsigned int w) {
    return __builtin_bit_cast(float, w & 0xffff0000u);
}
__device__ __forceinline__ unsigned pack2(float a, float b) {
    return (unsigned)f2bf(a) | ((unsigned)f2bf(b) << 16);
}
__device__ __forceinline__ void store_val(bf16* p, float v) { *p = __float2bfloat16(v); }

__device__ __forceinline__ void async_copy16(const void* g, void* l) {
    __builtin_amdgcn_global_load_lds((const __attribute__((address_space(1))) void*)g,
                                     (__attribute__((address_space(3))) void*)l, 16, 0, 0);
}

// fp32->bf16 cast of one float4 chunk (rides along in CSR-chain kernels' idle BW)
__device__ __forceinline__ void cast_chunk(const float* __restrict__ x,
                                           unsigned short* __restrict__ y, int i) {
    float4 v = ((const float4*)x)[i];
    ushort4 o;
    o.x = f2bf(v.x); o.y = f2bf(v.y); o.z = f2bf(v.z); o.w = f2bf(v.w);
    ((ushort4*)y)[i] = o;
}

// ================= CSR build (each kernel carries CAST_CHUNK cast blocks) =================
__global__ void k_zero_int(int* __restrict__ p, int n,
                           const float* __restrict__ cx, unsigned short* __restrict__ cy,
                           int castBase, int nbMain) {
    if ((int)blockIdx.x >= nbMain) {
        cast_chunk(cx, cy, (castBase + (int)blockIdx.x - nbMain) * 256 + (int)threadIdx.x);
        return;
    }
    int i = blockIdx.x * 256 + threadIdx.x;
    if (i < n) p[i] = 0;
}
__global__ void k_count_deg(const int* __restrict__ dst, int* __restrict__ deg,
                            const float* __restrict__ cx, unsigned short* __restrict__ cy,
                            int castBase, int nbMain) {
    if ((int)blockIdx.x >= nbMain) {
        cast_chunk(cx, cy, (castBase + (int)blockIdx.x - nbMain) * 256 + (int)threadIdx.x);
        return;
    }
    int e = blockIdx.x * 256 + threadIdx.x;
    if (e < N_EDGES) atomicAdd(&deg[dst[e]], 1);
}
// block sums for scan + dinv (merged: same pass over deg)
__global__ void k_block_sums(const int* __restrict__ deg, int* __restrict__ bsum,
                             float* __restrict__ dinv,
                             const float* __restrict__ cx, unsigned short* __restrict__ cy,
                             int castBase, int nbMain) {
    if ((int)blockIdx.x >= nbMain) {
        cast_chunk(cx, cy, (castBase + (int)blockIdx.x - nbMain) * 256 + (int)threadIdx.x);
        return;
    }
    __shared__ int s[256];
    int t = threadIdx.x;
    int i = blockIdx.x * 256 + t;
    int v = (i < N_NODES) ? deg[i] : 0;
    s[t] = v;
    if (i < N_NODES) dinv[i] = rsqrtf((float)(v + 1));  // +1 self loop
    __syncthreads();
    for (int off = 128; off > 0; off >>= 1) {
        if (t < off) s[t] += s[t + off];
        __syncthreads();
    }
    if (t == 0) bsum[blockIdx.x] = s[0];
}
__global__ void k_scan_bsums(int* __restrict__ bsum, int nb) {
    __shared__ int s[512];
    int t = threadIdx.x;
    int v = (t < nb) ? bsum[t] : 0;
    s[t] = v;
    __syncthreads();
    for (int off = 1; off < 512; off <<= 1) {
        int u = (t >= off) ? s[t - off] : 0;
        __syncthreads();
        s[t] += u;
        __syncthreads();
    }
    if (t < nb) bsum[t] = s[t] - v;  // exclusive
}
__global__ void k_row_ptr(const int* __restrict__ deg, const int* __restrict__ bsum,
                          int* __restrict__ row_ptr,
                          const float* __restrict__ cx, unsigned short* __restrict__ cy,
                          int castBase, int nbMain) {
    if ((int)blockIdx.x >= nbMain) {
        cast_chunk(cx, cy, (castBase + (int)blockIdx.x - nbMain) * 256 + (int)threadIdx.x);
        return;
    }
    __shared__ int s[256];
    int t = threadIdx.x;
    int i = blockIdx.x * 256 + t;
    int v = (i < N_NODES) ? deg[i] : 0;
    s[t] = v;
    __syncthreads();
    for (int off = 1; off < 256; off <<= 1) {
        int u = (t >= off) ? s[t - off] : 0;
        __syncthreads();
        s[t] += u;
        __syncthreads();
    }
    if (i < N_NODES) row_ptr[i] = bsum[blockIdx.x] + s[t] - v;  // exclusive
    if (blockIdx.x == 0 && t == 0) row_ptr[N_NODES] = N_EDGES;
}
// scatter also precomputes per-edge weight wedge = dinv[d]*dinv[s], the original
// edge id, and the row (dst) node of each CSR slot for edge-parallel CSR passes.
__global__ void k_scatter(const int* __restrict__ src, const int* __restrict__ dst,
                          const int* __restrict__ row_ptr, int* __restrict__ cursor,
                          const float* __restrict__ dinv,
                          int* __restrict__ col, float* __restrict__ wedge,
                          int* __restrict__ eid, int* __restrict__ rowid,
                          const float* __restrict__ cx, unsigned short* __restrict__ cy,
                          int castBase, int nbMain) {
    if ((int)blockIdx.x >= nbMain) {
        cast_chunk(cx, cy, (castBase + (int)blockIdx.x - nbMain) * 256 + (int)threadIdx.x);
        return;
    }
    int e = blockIdx.x * 256 + threadIdx.x;
    if (e < N_EDGES) {
        int d = dst[e], s = src[e];
        int p = atomicAdd(&cursor[d], 1);
        int idx = row_ptr[d] + p;
        col[idx] = s;
        wedge[idx] = dinv[d] * dinv[s];
        eid[idx] = e;
        rowid[idx] = d;
    }
}

// ================= weight transposes (W1, W2 only) =================
__global__ void k_transpose_all(const float* __restrict__ W1, const float* __restrict__ W2,
                                bf16* __restrict__ wt) {
    int which = blockIdx.x >> 8;  // 0..1
    int idx = ((blockIdx.x & 255) << 8) + threadIdx.x;
    int n = idx >> 8, k = idx & 255;
    const float* W = which ? W2 : W1;
    wt[(size_t)which * 65536 + (size_t)n * 256 + k] =
        __float2bfloat16(W[(size_t)k * 256 + n]);
}

// ============ fused layer-3 + link-pred weights (+ fused bias in block 256) ============
// W3fc^T[n][k] = sum_j W3[k][j] * F[j][n], F[j][n] = fc1_w[(n<256? j : 256+j)][n&255]
// Output 512x256 = 2*65536 bf16. Block 256: b3fc[n] = sum_j b3[j]*F[j][n] + (n<256?fc1_b[n]:0)
__global__ void k_fuse_w(const float* __restrict__ W3, const float* __restrict__ fc1w,
                         const float* __restrict__ b3, const float* __restrict__ fc1b,
                         bf16* __restrict__ wtf, float* __restrict__ bout) {
    int n = threadIdx.x;      // 0..511
    int nc = n & 255;
    size_t ro = (n < 256) ? 0 : 256;
    if (blockIdx.x == 256) {  // fused bias (uniform per block, no barrier crossed)
        float acc = (n < 256) ? fc1b[n] : 0.f;
#pragma unroll 4
        for (int j = 0; j < 256; ++j)
            acc += b3[j] * fc1w[(ro + j) * 256 + nc];
        bout[n] = acc;
        return;
    }
    __shared__ float w3row[256];
    int k = blockIdx.x;       // 0..255
    if (n < 256) w3row[n] = W3[(size_t)k * 256 + n];
    __syncthreads();
    float acc = 0.f;
#pragma unroll 4
    for (int j = 0; j < 256; ++j)
        acc += w3row[j] * fc1w[(ro + j) * 256 + nc];
    wtf[(size_t)n * 256 + k] = __float2bfloat16(acc);
}

// ====== bf16 MFMA GEMM — 8 waves / 512 threads, 32KB LDS, occupancy-first ======
// C[M x (NX*128)] = A @ Bt^T + bias. 128x128 tile, BK=64, 4 K-steps.
// Wave tile 32x64 (acc[2][4] = 32 VGPR) so __launch_bounds__(512,6) caps VGPR
// ~85 -> 6 waves/SIMD = 24 waves/CU: latency hidden by TLP.
// STATS: per-row-tile column sum/sumsq partials (BN input stats) -> part.
template <int NX, bool BIAS, bool STATS>
__global__ __launch_bounds__(512, 6) void k_gemm_mfma(const bf16* __restrict__ A,
                                                      const bf16* __restrict__ Bt,
                                                      bf16* __restrict__ C, int M, int ldc,
                                                      const float* __restrict__ bias,
                                                      float* __restrict__ part) {
    constexpr int LOG2NX = (NX == 4) ? 2 : 1;
    int id = blockIdx.x;
    int rg = (id & 7) + 8 * (id >> (3 + LOG2NX));
    int ct = (id >> 3) & (NX - 1);
    if (rg >= Y_TILES) return;
    const int row0 = rg * 128;
    const int col0 = ct * 128;

    __shared__ bf16 As[128 * 64];   // 16 KB
    __shared__ bf16 Bs[128 * 64];   // 16 KB
    __shared__ float sS[4][128];
    __shared__ float sQ[4][128];
    const int tid = threadIdx.x;
    const int lane = tid & 63;
    const int w = tid >> 6;          // 0..7
    const int wr = w >> 1, wc = w & 1;   // wr 0..3 (32-row strips), wc 0..1 (64-col)
    const int lr = lane & 15, quad = lane >> 4;

    f32x4_t acc[2][4] = {};

    for (int k0 = 0; k0 < 256; k0 += 64) {
#pragma unroll
        for (int i = 0; i < 2; ++i) {
            int j = i * 512 + tid;        // 1024 chunks of 16B per buffer
            int r = j >> 3, c = j & 7;
            int gk = ((c ^ (r & 7)) << 3);
            int gr = row0 + r; gr = gr < M ? gr : M - 1;
            async_copy16(A + (size_t)gr * 256 + k0 + gk, (void*)(As + j * 8));
            async_copy16(Bt + (size_t)(col0 + r) * 256 + k0 + gk, (void*)(Bs + j * 8));
        }
        __syncthreads();
#pragma unroll
        for (int ks = 0; ks < 2; ++ks) {
            bf16x8_t af[2], bfr[4];
#pragma unroll
            for (int mi = 0; mi < 2; ++mi) {
                int m = wr * 32 + mi * 16 + lr;
                int c = (ks * 4 + quad) ^ (m & 7);
                af[mi] = *(const bf16x8_t*)(As + m * 64 + c * 8);
            }
#pragma unroll
            for (int ni = 0; ni < 4; ++ni) {
                int n = wc * 64 + ni * 16 + lr;
                int c = (ks * 4 + quad) ^ (n & 7);
                bfr[ni] = *(const bf16x8_t*)(Bs + n * 64 + c * 8);
            }
#pragma unroll
            for (int mi = 0; mi < 2; ++mi)
#pragma unroll
                for (int ni = 0; ni < 4; ++ni)
                    acc[mi][ni] = __builtin_amdgcn_mfma_f32_16x16x32_bf16(
                        af[mi], bfr[ni], acc[mi][ni], 0, 0, 0);
        }
        __syncthreads();
    }
    // bias into acc (so stats include it)
#pragma unroll
    for (int ni = 0; ni < 4; ++ni) {
        int colg = col0 + wc * 64 + ni * 16 + lr;
        float bv = BIAS ? bias[colg] : 0.f;
#pragma unroll
        for (int mi = 0; mi < 2; ++mi)
#pragma unroll
            for (int r = 0; r < 4; ++r) acc[mi][ni][r] += bv;
    }
    if (STATS) {
        float cs[4] = {}, cq[4] = {};
#pragma unroll
        for (int mi = 0; mi < 2; ++mi)
#pragma unroll
            for (int r = 0; r < 4; ++r) {
                int row = row0 + wr * 32 + mi * 16 + quad * 4 + r;
                if (row < M) {
#pragma unroll
                    for (int ni = 0; ni < 4; ++ni) {
                        float v = acc[mi][ni][r];
                        cs[ni] += v;
                        cq[ni] += v * v;
                    }
                }
            }
        // sum across the 4 quads (lanes lr, lr+16, lr+32, lr+48)
#pragma unroll
        for (int ni = 0; ni < 4; ++ni) {
            cs[ni] += __shfl_xor(cs[ni], 16, 64);
            cs[ni] += __shfl_xor(cs[ni], 32, 64);
            cq[ni] += __shfl_xor(cq[ni], 16, 64);
            cq[ni] += __shfl_xor(cq[ni], 32, 64);
        }
        if (quad == 0) {
#pragma unroll
            for (int ni = 0; ni < 4; ++ni) {
                int cc = wc * 64 + ni * 16 + lr;
                sS[wr][cc] = cs[ni];
                sQ[wr][cc] = cq[ni];
            }
        }
        __syncthreads();
        if (tid < 128) {
            float ss = sS[0][tid] + sS[1][tid] + sS[2][tid] + sS[3][tid];
            float qq = sQ[0][tid] + sQ[1][tid] + sQ[2][tid] + sQ[3][tid];
            int cg = col0 + tid;
            part[(size_t)rg * 512 + cg] = ss;
            part[(size_t)rg * 512 + 256 + cg] = qq;
        }
    }
#pragma unroll
    for (int mi = 0; mi < 2; ++mi) {
#pragma unroll
        for (int r = 0; r < 4; ++r) {
            int row = row0 + wr * 32 + mi * 16 + quad * 4 + r;
            if (row < M) {
#pragma unroll
                for (int ni = 0; ni < 4; ++ni) {
                    int colg = col0 + wc * 64 + ni * 16 + lr;
                    store_val(C + (size_t)row * ldc + colg, acc[mi][ni][r]);
                }
            }
        }
    }
}

// expand a uint4 of 8 bf16 into 8 floats, optionally applying BN(scale,shift)+relu
template <bool BN>
__device__ __forceinline__ void expand8(uint4 m, const float* sc, const float* sh, float* r) {
    r[0] = bflo(m.x); r[1] = bfhi(m.x); r[2] = bflo(m.y); r[3] = bfhi(m.y);
    r[4] = bflo(m.z); r[5] = bfhi(m.z); r[6] = bflo(m.w); r[7] = bfhi(m.w);
    if (BN) {
#pragma unroll
        for (int i = 0; i < 8; ++i) r[i] = fmaxf(r[i] * sc[i] + sh[i], 0.f);
    }
}

// ===== CSR aggregation y = A_hat x' (+bias) : 32 lanes/node, 32 nodes/block.
// Sequential per-node edge loop, 2 outstanding gathers per chain (r8-proven).
// BN: x' = relu(x*scale+shift) on the fly. STATS: post-bias per-block column
// sum/sumsq partials -> part[block][512] (BN stats over the OUTPUT h).
template <bool BN, bool STATS>
__global__ __launch_bounds__(256) void k_agg_csr(const unsigned short* __restrict__ x,
                                                 const int* __restrict__ row_ptr,
                                                 const int* __restrict__ col,
                                                 const float* __restrict__ wedge,
                                                 const float* __restrict__ dinv,
                                                 const float* __restrict__ scale,
                                                 const float* __restrict__ shift,
                                                 const float* __restrict__ bias,
                                                 bf16* __restrict__ out,
                                                 float* __restrict__ part) {
    __shared__ float sred[8][256];
    __shared__ float qred[8][256];
    int g = threadIdx.x >> 5, lh = threadIdx.x & 31;  // 8 half-waves x 32 lanes
    int base = blockIdx.x * 32 + g * 4;               // exact: AGG_BLOCKS*32 == N_NODES
    const uint4* xv = (const uint4*)x;                // bf16 row = 32 uint4
    float sc[8], sh[8], bs[8];
    if (BN) {
        float4 a = ((const float4*)scale)[lh * 2];
        float4 b = ((const float4*)scale)[lh * 2 + 1];
        float4 c = ((const float4*)shift)[lh * 2];
        float4 d = ((const float4*)shift)[lh * 2 + 1];
        sc[0] = a.x; sc[1] = a.y; sc[2] = a.z; sc[3] = a.w;
        sc[4] = b.x; sc[5] = b.y; sc[6] = b.z; sc[7] = b.w;
        sh[0] = c.x; sh[1] = c.y; sh[2] = c.z; sh[3] = c.w;
        sh[4] = d.x; sh[5] = d.y; sh[6] = d.z; sh[7] = d.w;
    }
    if (STATS) {
        float4 e = ((const float4*)bias)[lh * 2];
        float4 f = ((const float4*)bias)[lh * 2 + 1];
        bs[0] = e.x; bs[1] = e.y; bs[2] = e.z; bs[3] = e.w;
        bs[4] = f.x; bs[5] = f.y; bs[6] = f.z; bs[7] = f.w;
    }
    float s8[8] = {}, q8[8] = {};
#pragma unroll
    for (int n = 0; n < 4; ++n) {
        int node = base + n;
        int beg = row_ptr[node], end = row_ptr[node + 1];
        float dv = dinv[node];
        float s2 = dv * dv;
        uint4 xr = xv[(size_t)node * 32 + lh];
        float rs[8];
        expand8<BN>(xr, sc, sh, rs);
        float a[8];
#pragma unroll
        for (int t = 0; t < 8; ++t) a[t] = s2 * rs[t];
        int i = beg;
        for (; i + 2 <= end; i += 2) {  // 2 outstanding gathers per chain
            int sa = col[i], sb = col[i + 1];
            float wa = wedge[i], wb = wedge[i + 1];
            uint4 ma = xv[(size_t)sa * 32 + lh];
            uint4 mb = xv[(size_t)sb * 32 + lh];
            float ra[8], rb[8];
            expand8<BN>(ma, sc, sh, ra);
            expand8<BN>(mb, sc, sh, rb);
#pragma unroll
            for (int t = 0; t < 8; ++t) a[t] += wa * ra[t] + wb * rb[t];
        }
        if (i < end) {
            int sa = col[i];
            float wa = wedge[i];
            uint4 ma = xv[(size_t)sa * 32 + lh];
            float ra[8];
            expand8<BN>(ma, sc, sh, ra);
#pragma unroll
            for (int t = 0; t < 8; ++t) a[t] += wa * ra[t];
        }
        if (STATS) {
#pragma unroll
            for (int t = 0; t < 8; ++t) {
                a[t] += bs[t];
                s8[t] += a[t];
                q8[t] += a[t] * a[t];
            }
        }
        uint4 o;
        o.x = pack2(a[0], a[1]); o.y = pack2(a[2], a[3]);
        o.z = pack2(a[4], a[5]); o.w = pack2(a[6], a[7]);
        ((uint4*)(out + (size_t)node * CH))[lh] = o;
    }
    if (STATS) {
#pragma unroll
        for (int j = 0; j < 8; ++j) {
            sred[g][lh * 8 + j] = s8[j];
            qred[g][lh * 8 + j] = q8[j];
        }
        __syncthreads();
        int t = threadIdx.x;  // channel 0..255
        float ss = 0.f, qq = 0.f;
#pragma unroll
        for (int gg = 0; gg < 8; ++gg) {
            ss += sred[gg][t];
            qq += qred[gg][t];
        }
        part[(size_t)blockIdx.x * 512 + t] = ss;
        part[(size_t)blockIdx.x * 512 + 256 + t] = qq;
    }
}

// one wave per channel: lanes stride over npart partials, shuffle-reduce
__global__ __launch_bounds__(256) void k_bn_finalize(const float* __restrict__ part,
                                                     const float* __restrict__ g,
                                                     const float* __restrict__ be,
                                                     float* __restrict__ scale,
                                                     float* __restrict__ shift, int npart) {
    int wave = threadIdx.x >> 6, lane = threadIdx.x & 63;
    int c = blockIdx.x * 4 + wave;  // 0..255
    float s = 0.f, q = 0.f;
    for (int j = lane; j < npart; j += 64) {
        s += part[(size_t)j * 512 + c];
        q += part[(size_t)j * 512 + 256 + c];
    }
#pragma unroll
    for (int off = 32; off > 0; off >>= 1) {
        s += __shfl_down(s, off, 64);
        q += __shfl_down(q, off, 64);
    }
    if (lane == 0) {
        float mu = s * (1.0f / N_NODES);
        float var = q * (1.0f / N_NODES) - mu * mu;
        float sc = g[c] * rsqrtf(var + EPS);
        scale[c] = sc;
        shift[c] = be[c] - mu * sc;
    }
}

// ======= edge scoring: edge-parallel over CSR (dst-sorted) slots =======
// 4 slots/wave, 16 lanes each, 16 ch/lane; consecutive quarters share the
// same/nearby dst rows (v[dst] L1/L2-resident). Blocks XCD-swizzled (bijective).
__global__ __launch_bounds__(256) void k_edge_score(
        const unsigned short* __restrict__ uv,
        const int* __restrict__ col, const int* __restrict__ eid,
        const int* __restrict__ rowid, const int* __restrict__ neg,
        const float* __restrict__ fc2_w, const float* __restrict__ fc2_b,
        float* __restrict__ out) {
    constexpr int NWG = 18750;          // N_EDGES / 16
    constexpr int Q = NWG / 8, R = NWG % 8;  // 2343, 6
    int bid = blockIdx.x;
    int xcd = bid & 7, ord = bid >> 3;
    int swz = ((xcd < R) ? xcd * (Q + 1) : R * (Q + 1) + (xcd - R) * Q) + ord;
    int wave = threadIdx.x >> 6, lane = threadIdx.x & 63;
    int qtr = lane >> 4, l = lane & 15;
    int i = swz * 16 + wave * 4 + qtr;  // CSR slot, NWG*16 == N_EDGES exactly
    int s = col[i], d = rowid[i], e = eid[i];
    int g = neg[e];
    const uint4* uvv = (const uint4*)uv;  // row = 64 uint4 (u: 0..31, v: 32..63)
    uint4 u0 = uvv[(size_t)s * 64 + l * 2];
    uint4 u1 = uvv[(size_t)s * 64 + l * 2 + 1];
    uint4 p0 = uvv[(size_t)d * 64 + 32 + l * 2];
    uint4 p1 = uvv[(size_t)d * 64 + 33 + l * 2];
    uint4 n0 = uvv[(size_t)g * 64 + 32 + l * 2];
    uint4 n1 = uvv[(size_t)g * 64 + 33 + l * 2];
    float4 w0 = ((const float4*)fc2_w)[l * 4];
    float4 w1 = ((const float4*)fc2_w)[l * 4 + 1];
    float4 w2 = ((const float4*)fc2_w)[l * 4 + 2];
    float4 w3 = ((const float4*)fc2_w)[l * 4 + 3];

    float t0 = bflo(u0.x), t1 = bfhi(u0.x), t2 = bflo(u0.y), t3 = bfhi(u0.y);
    float t4 = bflo(u0.z), t5 = bfhi(u0.z), t6 = bflo(u0.w), t7 = bfhi(u0.w);
    float t8 = bflo(u1.x), t9 = bfhi(u1.x), ta = bflo(u1.y), tb = bfhi(u1.y);
    float tc = bflo(u1.z), td = bfhi(u1.z), te = bflo(u1.w), tf = bfhi(u1.w);

    float accp =
        fmaxf(t0 + bflo(p0.x), 0.f) * w0.x + fmaxf(t1 + bfhi(p0.x), 0.f) * w0.y +
        fmaxf(t2 + bflo(p0.y), 0.f) * w0.z + fmaxf(t3 + bfhi(p0.y), 0.f) * w0.w +
        fmaxf(t4 + bflo(p0.z), 0.f) * w1.x + fmaxf(t5 + bfhi(p0.z), 0.f) * w1.y +
        fmaxf(t6 + bflo(p0.w), 0.f) * w1.z + fmaxf(t7 + bfhi(p0.w), 0.f) * w1.w +
        fmaxf(t8 + bflo(p1.x), 0.f) * w2.x + fmaxf(t9 + bfhi(p1.x), 0.f) * w2.y +
        fmaxf(ta + bflo(p1.y), 0.f) * w2.z + fmaxf(tb + bfhi(p1.y), 0.f) * w2.w +
        fmaxf(tc + bflo(p1.z), 0.f) * w3.x + fmaxf(td + bfhi(p1.z), 0.f) * w3.y +
        fmaxf(te + bflo(p1.w), 0.f) * w3.z + fmaxf(tf + bfhi(p1.w), 0.f) * w3.w;
    float accn =
        fmaxf(t0 + bflo(n0.x), 0.f) * w0.x + fmaxf(t1 + bfhi(n0.x), 0.f) * w0.y +
        fmaxf(t2 + bflo(n0.y), 0.f) * w0.z + fmaxf(t3 + bfhi(n0.y), 0.f) * w0.w +
        fmaxf(t4 + bflo(n0.z), 0.f) * w1.x + fmaxf(t5 + bfhi(n0.z), 0.f) * w1.y +
        fmaxf(t6 + bflo(n0.w), 0.f) * w1.z + fmaxf(t7 + bfhi(n0.w), 0.f) * w1.w +
        fmaxf(t8 + bflo(n1.x), 0.f) * w2.x + fmaxf(t9 + bfhi(n1.x), 0.f) * w2.y +
        fmaxf(ta + bflo(n1.y), 0.f) * w2.z + fmaxf(tb + bfhi(n1.y), 0.f) * w2.w +
        fmaxf(tc + bflo(n1.z), 0.f) * w3.x + fmaxf(td + bfhi(n1.z), 0.f) * w3.y +
        fmaxf(te + bflo(n1.w), 0.f) * w3.z + fmaxf(tf + bfhi(n1.w), 0.f) * w3.w;
#pragma unroll
    for (int off = 8; off > 0; off >>= 1) {
        accp += __shfl_down(accp, off, 64);
        accn += __shfl_down(accn, off, 64);
    }
    if (l == 0) {
        float bb = fc2_b[0];
        out[e] = 1.0f / (1.0f + expf(-(accp + bb)));
        out[N_EDGES + e] = 1.0f / (1.0f + expf(-(accn + bb)));
    }
}

extern "C" void kernel_launch(void* const* d_in, const int* in_sizes, int n_in,
                              void* d_out, int out_size, void* d_ws, size_t ws_size,
                              hipStream_t stream) {
    const float* node_feat = (const float*)d_in[0];
    const int* src = (const int*)d_in[1];
    const int* dst = (const int*)d_in[2];
    const int* neg = (const int*)d_in[3];
    const float* W1 = (const float*)d_in[4];  const float* b1 = (const float*)d_in[5];
    const float* W2 = (const float*)d_in[6];  const float* b2 = (const float*)d_in[7];
    const float* W3 = (const float*)d_in[8];  const float* b3 = (const float*)d_in[9];
    const float* g1 = (const float*)d_in[10]; const float* be1 = (const float*)d_in[11];
    const float* g2 = (const float*)d_in[12]; const float* be2 = (const float*)d_in[13];
    const float* fc1_w = (const float*)d_in[14]; const float* fc1_b = (const float*)d_in[15];
    const float* fc2_w = (const float*)d_in[16]; const float* fc2_b = (const float*)d_in[17];
    float* out = (float*)d_out;

    // ---- workspace layout ----
    const size_t NF = (size_t)N_NODES * CH;  // 25,600,000
    bf16* UV = (bf16*)d_ws;                  // [node][512] u|v (2*NF)
    bf16* Xbf = UV + 2 * NF;                 // ping buffer (NF)
    bf16* XwBf = Xbf + NF;                   // pong buffer (NF)
    bf16* wt = XwBf + NF;                    // 4*65536: W1t(1) W2t(1) W3fc_t(2 - 512x256)
    float* dinv = (float*)(wt + 4 * 65536);
    float* bnpart = dinv + N_NODES;          // AGG_BLOCKS * 512 (6.4 MB, covers both uses)
    float* scale = bnpart + (size_t)AGG_BLOCKS * 512;
    float* shift = scale + CH;
    float* b3fc = shift + CH;                // 512 fused bias
    float* wedge = b3fc + 512;               // E floats
    int* ideg = (int*)(wedge + N_EDGES);     // N (cursor follows: zeroed together)
    int* cursor = ideg + N_NODES;
    int* row_ptr = cursor + N_NODES;
    int* col = row_ptr + N_NODES + 1;
    int* eid = col + N_EDGES;                // E ints (original edge id per CSR slot)
    int* rowid = eid + N_EDGES;              // E ints (dst node per CSR slot)
    int* bsum = rowid + N_EDGES;             // 512
    (void)ws_size;

    int gemmBlocks = 2 * Y_TILES_PAD;          // 1568 (N=256, NX=2)
    int uvBlocks = 4 * Y_TILES_PAD;            // 3136 (N=512, NX=4)
    int nodeBlocks = (N_NODES + 255) / 256;    // 391
    int edgeBlocks = (N_EDGES + 255) / 256;    // 1172
    int zeroBlocks = (2 * N_NODES + 255) / 256;// 782
    int scoreBlocks = N_EDGES / 16;            // 18750 (4 CSR slots per wave)
    unsigned short* Xc = (unsigned short*)Xbf; // cast destination

    // ---- CSR build + dinv + edge weights (each kernel carries 5000 cast blocks;
    //      5 x 5000 x 1024 elems == NF exactly -> Xbf fully cast before gemm1) ----
    k_zero_int<<<zeroBlocks + CAST_CHUNK, 256, 0, stream>>>(
        ideg, 2 * N_NODES, node_feat, Xc, 0 * CAST_CHUNK, zeroBlocks);
    k_count_deg<<<edgeBlocks + CAST_CHUNK, 256, 0, stream>>>(
        dst, ideg, node_feat, Xc, 1 * CAST_CHUNK, edgeBlocks);
    k_block_sums<<<nodeBlocks + CAST_CHUNK, 256, 0, stream>>>(
        ideg, bsum, dinv, node_feat, Xc, 2 * CAST_CHUNK, nodeBlocks);
    k_scan_bsums<<<1, 512, 0, stream>>>(bsum, nodeBlocks);
    k_row_ptr<<<nodeBlocks + CAST_CHUNK, 256, 0, stream>>>(
        ideg, bsum, row_ptr, node_feat, Xc, 3 * CAST_CHUNK, nodeBlocks);
    k_scatter<<<edgeBlocks + CAST_CHUNK, 256, 0, stream>>>(
        src, dst, row_ptr, cursor, dinv, col, wedge, eid, rowid,
        node_feat, Xc, 4 * CAST_CHUNK, edgeBlocks);

    // ---- weight prep: W1t, W2t transposes; fused W3@[Wu|Wv] (+bias, block 256) ----
    k_transpose_all<<<512, 256, 0, stream>>>(W1, W2, wt);
    k_fuse_w<<<257, 512, 0, stream>>>(W3, fc1_w, b3, fc1_b, wt + 2 * 65536, b3fc);

    // ---- layer 1: xw1 = X@W1 ; h1 = A_hat xw1 + b1 (stats in agg) ----
    k_gemm_mfma<2, false, false><<<gemmBlocks, 512, 0, stream>>>(
        Xbf, wt, XwBf, N_NODES, 256, nullptr, nullptr);
    k_agg_csr<false, true><<<AGG_BLOCKS, 256, 0, stream>>>(
        (unsigned short*)XwBf, row_ptr, col, wedge, dinv, nullptr, nullptr, b1, Xbf, bnpart);
    k_bn_finalize<<<64, 256, 0, stream>>>(bnpart, g1, be1, scale, shift, AGG_BLOCKS);

    // ---- layer 2: y2 = A_hat relu(BN(h1)) ; h2 = y2@W2 + b2 (stats in epilogue) ----
    k_agg_csr<true, false><<<AGG_BLOCKS, 256, 0, stream>>>(
        (unsigned short*)Xbf, row_ptr, col, wedge, dinv, scale, shift, nullptr, XwBf, nullptr);
    k_gemm_mfma<2, true, true><<<gemmBlocks, 512, 0, stream>>>(
        XwBf, wt + 65536, Xbf, N_NODES, 256, b2, bnpart);
    k_bn_finalize<<<64, 256, 0, stream>>>(bnpart, g2, be2, scale, shift, Y_TILES);

    // ---- layer 3 + link pred: y3 = A_hat relu(BN(h2)) ; UV = y3@W3fc + b3fc ----
    k_agg_csr<true, false><<<AGG_BLOCKS, 256, 0, stream>>>(
        (unsigned short*)Xbf, row_ptr, col, wedge, dinv, scale, shift, nullptr, XwBf, nullptr);
    k_gemm_mfma<4, true, false><<<uvBlocks, 512, 0, stream>>>(
        XwBf, wt + 2 * 65536, UV, N_NODES, 512, b3fc, nullptr);

    // ---- edge scoring ----
    k_edge_score<<<scoreBlocks, 256, 0, stream>>>((unsigned short*)UV, col, eid, rowid, neg,
                                                  fc2_w, fc2_b, out);
}